// Round 2
// baseline (240.570 us; speedup 1.0000x reference)
//
#include <hip/hip_runtime.h>
#include <cstdint>

// Problem constants
constexpr int kN   = 4;
constexpr int kC   = 256;
constexpr int kS   = 2304;   // 48*48
constexpr int kDK  = 256;
constexpr int kDV  = 256;
constexpr int kDH  = 32;     // head dim
constexpr int kO   = 768;    // 2*DK + DV

typedef __bf16 bf16x8 __attribute__((ext_vector_type(8)));
typedef float  f32x4  __attribute__((ext_vector_type(4)));

union U4 { uint4 u; bf16x8 v; unsigned short s[8]; };
union F4 { float4 f; float a[4]; };

__device__ inline float bf2f(unsigned short h) {
    unsigned int u = ((unsigned int)h) << 16;
    return __builtin_bit_cast(float, u);
}
__device__ inline unsigned short f2bf(float f) {
    unsigned int u = __builtin_bit_cast(unsigned int, f);
    u += 0x7fff + ((u >> 16) & 1);   // RNE; all values finite here
    return (unsigned short)(u >> 16);
}
// fp32 -> bf16 (hi) + bf16 (residual lo); x ~= hi + lo with ~2^-17 rel error
__device__ inline void split2(float v, unsigned short& h, unsigned short& l) {
    h = f2bf(v);
    l = f2bf(v - bf2f(h));
}

// ---------------------------------------------------------------------------
// Stage 0: transpose x[n][c][s] -> xT[n][s][c]  (fp32)
// ---------------------------------------------------------------------------
__global__ __launch_bounds__(256) void transpose_x(const float* __restrict__ x,
                                                   float* __restrict__ xT) {
    __shared__ float t[32][33];   // +1 pad: conflict-free column reads
    int n  = blockIdx.z;
    int ct = blockIdx.y;     // 256/32 = 8
    int st = blockIdx.x;     // 2304/32 = 72
    int lx = threadIdx.x & 31;
    int ly = threadIdx.x >> 5;   // 0..7
    const float* xb = x + (size_t)n * kC * kS;
#pragma unroll
    for (int i = 0; i < 4; i++) {
        int c = ct * 32 + ly + i * 8;
        t[ly + i * 8][lx] = xb[(size_t)c * kS + st * 32 + lx];
    }
    __syncthreads();
    float* xTb = xT + (size_t)n * kS * kC;
#pragma unroll
    for (int i = 0; i < 4; i++) {
        int s = st * 32 + ly + i * 8;
        xTb[(size_t)s * kC + ct * 32 + lx] = t[lx][ly + i * 8];
    }
}

// ---------------------------------------------------------------------------
// gemm_bt: C[M][Ncol] = A[M][K] * B[Ncol][K]^T  (+bias), fp32 in/out.
// Internally split-bf16: A=Ah+Al, B=Bh+Bl; acc += AhBh + AhBl + AlBh (fp32 MFMA acc).
// MODE 0: bias indexed by col, scale cols [DK, 2*DK) by DK^-0.5 (stage 1)
// MODE 1: bias indexed by row (stage 3)
// Block: 256 thr = 4 waves; tile 128x128, BK=32; wave computes 64x64 (4x4 frags)
// ---------------------------------------------------------------------------
template <int MODE>
__global__ __launch_bounds__(256) void gemm_bt(const float* __restrict__ A,
                                               const float* __restrict__ B,
                                               const float* __restrict__ bias,
                                               float* __restrict__ C,
                                               int K, int lda, int ldb, int ldc,
                                               long long strideA, long long strideB,
                                               long long strideC) {
    int n = blockIdx.z;
    A += (size_t)n * strideA;
    B += (size_t)n * strideB;
    C += (size_t)n * strideC;
    int m0 = blockIdx.y * 128;
    int n0 = blockIdx.x * 128;

    __shared__ unsigned short Ah[128 * 40];  // row stride 40 shorts = 80B (16B-aligned rows)
    __shared__ unsigned short Al[128 * 40];
    __shared__ unsigned short Bh[128 * 40];
    __shared__ unsigned short Bl[128 * 40];

    int tid  = threadIdx.x;
    int wid  = tid >> 6;
    int lane = tid & 63;
    int l15  = lane & 15;
    int quad = lane >> 4;
    int wm   = (wid & 1) * 64;
    int wn   = (wid >> 1) * 64;

    f32x4 acc[4][4] = {};

    for (int k0 = 0; k0 < K; k0 += 32) {
#pragma unroll
        for (int t = 0; t < 4; t++) {
            int chunk = tid + t * 256;          // 1024 float4 chunks per 128x32 fp32 tile
            int row   = chunk >> 3;             // 0..127
            int c4    = (chunk & 7) * 4;        // 0,4,...,28
            F4 ga; ga.f = *(const float4*)(A + (size_t)(m0 + row) * lda + k0 + c4);
            ushort4 hv, lv;
            split2(ga.a[0], hv.x, lv.x);
            split2(ga.a[1], hv.y, lv.y);
            split2(ga.a[2], hv.z, lv.z);
            split2(ga.a[3], hv.w, lv.w);
            *(ushort4*)(&Ah[row * 40 + c4]) = hv;
            *(ushort4*)(&Al[row * 40 + c4]) = lv;
            F4 gb; gb.f = *(const float4*)(B + (size_t)(n0 + row) * ldb + k0 + c4);
            split2(gb.a[0], hv.x, lv.x);
            split2(gb.a[1], hv.y, lv.y);
            split2(gb.a[2], hv.z, lv.z);
            split2(gb.a[3], hv.w, lv.w);
            *(ushort4*)(&Bh[row * 40 + c4]) = hv;
            *(ushort4*)(&Bl[row * 40 + c4]) = lv;
        }
        __syncthreads();

        bf16x8 ah[4], al[4], bh[4], bl[4];
#pragma unroll
        for (int mt = 0; mt < 4; mt++) {
            U4 u;
            u.u = *(const uint4*)(&Ah[(wm + mt * 16 + l15) * 40 + quad * 8]); ah[mt] = u.v;
            u.u = *(const uint4*)(&Al[(wm + mt * 16 + l15) * 40 + quad * 8]); al[mt] = u.v;
        }
#pragma unroll
        for (int nt = 0; nt < 4; nt++) {
            U4 u;
            u.u = *(const uint4*)(&Bh[(wn + nt * 16 + l15) * 40 + quad * 8]); bh[nt] = u.v;
            u.u = *(const uint4*)(&Bl[(wn + nt * 16 + l15) * 40 + quad * 8]); bl[nt] = u.v;
        }
#pragma unroll
        for (int mt = 0; mt < 4; mt++)
#pragma unroll
            for (int nt = 0; nt < 4; nt++) {
                acc[mt][nt] = __builtin_amdgcn_mfma_f32_16x16x32_bf16(ah[mt], bh[nt], acc[mt][nt], 0, 0, 0);
                acc[mt][nt] = __builtin_amdgcn_mfma_f32_16x16x32_bf16(ah[mt], bl[nt], acc[mt][nt], 0, 0, 0);
                acc[mt][nt] = __builtin_amdgcn_mfma_f32_16x16x32_bf16(al[mt], bh[nt], acc[mt][nt], 0, 0, 0);
            }
        __syncthreads();
    }

    // Epilogue: D[row][col], col = lane&15, row = quad*4 + reg  (m89-verified layout)
#pragma unroll
    for (int nt = 0; nt < 4; nt++) {
        int col = n0 + wn + nt * 16 + l15;
        float bcol = (MODE == 0) ? bias[col] : 0.0f;
        float scale = (MODE == 0 && col >= kDK && col < 2 * kDK) ? 0.0625f : 1.0f;
#pragma unroll
        for (int mt = 0; mt < 4; mt++) {
            int row = m0 + wm + mt * 16 + quad * 4;
#pragma unroll
            for (int r = 0; r < 4; r++) {
                float v = acc[mt][nt][r];
                if (MODE == 0) v = (v + bcol) * scale;
                else           v = v + bias[row + r];
                C[(size_t)(row + r) * ldc + col] = v;
            }
        }
    }
}

// ---------------------------------------------------------------------------
// Stage 2: attention. qkvT[n][s][o] fp32 (o: [0,256)=K, [256,512)=Q prescaled,
// [512,768)=V) -> attnT[n][s][dv] fp32, dv = h*32 + d.
// QK^T in split-bf16 (3 MFMAs); softmax max-free; PV single-bf16.
// Block: 256 thr = 4 waves; q-tile 128 rows (32/wave); t-tiles of 64.
// ---------------------------------------------------------------------------
__global__ __launch_bounds__(256) void attn_kernel(const float* __restrict__ qkvT,
                                                   float* __restrict__ attnT) {
    constexpr int KSd = 40;  // K-tile row stride (shorts)
    constexpr int VS  = 72;  // Vt row stride
    constexpr int PS  = 72;  // P row stride
    __shared__ unsigned short Kh[64 * KSd];       // [t][d] hi
    __shared__ unsigned short Kl[64 * KSd];       // [t][d] lo
    __shared__ unsigned short Vt[32 * VS];        // [d][t] (transposed, bf16)
    __shared__ unsigned short Pw[4][32 * PS];     // per-wave [sq][t]

    int qt = blockIdx.x, h = blockIdx.y, n = blockIdx.z;
    int tid  = threadIdx.x;
    int wid  = tid >> 6;
    int lane = tid & 63;
    int l15  = lane & 15;
    int quad = lane >> 4;

    int s0 = qt * 128 + wid * 32;
    const float* qb = qkvT + (size_t)n * kS * kO;

    // Q A-fragments (A[m=lane&15][k=quad*8+j]), split hi/lo; q already scaled by DK^-0.5
    bf16x8 qh[2], ql[2];
#pragma unroll
    for (int mt = 0; mt < 2; mt++) {
        const float* p = qb + (size_t)(s0 + mt * 16 + l15) * kO + kDK + h * kDH + quad * 8;
        F4 a0, a1; a0.f = *(const float4*)(p); a1.f = *(const float4*)(p + 4);
        U4 uh, ul;
#pragma unroll
        for (int j = 0; j < 4; j++) { split2(a0.a[j], uh.s[j], ul.s[j]); }
#pragma unroll
        for (int j = 0; j < 4; j++) { split2(a1.a[j], uh.s[j + 4], ul.s[j + 4]); }
        qh[mt] = uh.v; ql[mt] = ul.v;
    }

    f32x4 oacc[2][2] = {};
    float lsum[2][4] = {};

    for (int t0 = 0; t0 < kS; t0 += 64) {
        // stage K-tile [64][32] hi/lo
        {
            int row = tid >> 2, d0 = (tid & 3) * 8;
            const float* kp = qb + (size_t)(t0 + row) * kO + h * kDH + d0;
            F4 a0, a1; a0.f = *(const float4*)(kp); a1.f = *(const float4*)(kp + 4);
            U4 uh, ul;
#pragma unroll
            for (int j = 0; j < 4; j++) { split2(a0.a[j], uh.s[j], ul.s[j]); }
#pragma unroll
            for (int j = 0; j < 4; j++) { split2(a1.a[j], uh.s[j + 4], ul.s[j + 4]); }
            *(uint4*)(&Kh[row * KSd + d0]) = uh.u;
            *(uint4*)(&Kl[row * KSd + d0]) = ul.u;
            // stage V-tile transposed (bf16): lane = t, wave picks d-chunk
            int vt = tid & 63, vd0 = (tid >> 6) * 8;
            const float* vp = qb + (size_t)(t0 + vt) * kO + 2 * kDK + h * kDH + vd0;
            F4 v0, v1; v0.f = *(const float4*)(vp); v1.f = *(const float4*)(vp + 4);
#pragma unroll
            for (int j = 0; j < 4; j++) Vt[(vd0 + j) * VS + vt] = f2bf(v0.a[j]);
#pragma unroll
            for (int j = 0; j < 4; j++) Vt[(vd0 + 4 + j) * VS + vt] = f2bf(v1.a[j]);
        }
        __syncthreads();

        // logits: split-bf16, 3 MFMAs per 16x16 (sq x sk) tile, K=32 (= full head dim)
        bf16x8 kh[4], kl[4];
#pragma unroll
        for (int skt = 0; skt < 4; skt++) {
            U4 u;
            u.u = *(const uint4*)(&Kh[(skt * 16 + l15) * KSd + quad * 8]); kh[skt] = u.v;
            u.u = *(const uint4*)(&Kl[(skt * 16 + l15) * KSd + quad * 8]); kl[skt] = u.v;
        }
        f32x4 lg[2][4];
#pragma unroll
        for (int mt = 0; mt < 2; mt++)
#pragma unroll
            for (int skt = 0; skt < 4; skt++) {
                f32x4 z = {};
                z = __builtin_amdgcn_mfma_f32_16x16x32_bf16(qh[mt], kh[skt], z, 0, 0, 0);
                z = __builtin_amdgcn_mfma_f32_16x16x32_bf16(qh[mt], kl[skt], z, 0, 0, 0);
                z = __builtin_amdgcn_mfma_f32_16x16x32_bf16(ql[mt], kh[skt], z, 0, 0, 0);
                lg[mt][skt] = z;
            }

        // exp + row-sum + P -> LDS (bf16)
#pragma unroll
        for (int mt = 0; mt < 2; mt++) {
            float rs[4] = {0.f, 0.f, 0.f, 0.f};
#pragma unroll
            for (int skt = 0; skt < 4; skt++)
#pragma unroll
                for (int r = 0; r < 4; r++) {
                    float p = __expf(lg[mt][skt][r]);
                    rs[r] += p;
                    Pw[wid][(mt * 16 + quad * 4 + r) * PS + skt * 16 + l15] = f2bf(p);
                }
#pragma unroll
            for (int r = 0; r < 4; r++) {
                float v = rs[r];
                v += __shfl_xor(v, 1);
                v += __shfl_xor(v, 2);
                v += __shfl_xor(v, 4);
                v += __shfl_xor(v, 8);
                lsum[mt][r] += v;   // all 16 lanes of the quad hold the full row sum
            }
        }

        // PV: O[sq][d] += P[sq][t] * V[t][d]; B-operand from transposed Vt
#pragma unroll
        for (int kt = 0; kt < 2; kt++) {
            bf16x8 vf[2];
#pragma unroll
            for (int dt = 0; dt < 2; dt++) {
                U4 u; u.u = *(const uint4*)(&Vt[(dt * 16 + l15) * VS + kt * 32 + quad * 8]);
                vf[dt] = u.v;
            }
#pragma unroll
            for (int mt = 0; mt < 2; mt++) {
                U4 u; u.u = *(const uint4*)(&Pw[wid][(mt * 16 + l15) * PS + kt * 32 + quad * 8]);
                bf16x8 pf = u.v;
#pragma unroll
                for (int dt = 0; dt < 2; dt++)
                    oacc[mt][dt] = __builtin_amdgcn_mfma_f32_16x16x32_bf16(pf, vf[dt],
                                                                           oacc[mt][dt], 0, 0, 0);
            }
        }
        __syncthreads();
    }

    // epilogue: divide by row sums, write attnT[n][s][h*32 + d] fp32
    float* ob = attnT + (size_t)n * kS * kDV;
#pragma unroll
    for (int mt = 0; mt < 2; mt++)
#pragma unroll
        for (int dt = 0; dt < 2; dt++)
#pragma unroll
            for (int r = 0; r < 4; r++) {
                int s = s0 + mt * 16 + quad * 4 + r;
                ob[(size_t)s * kDV + h * kDH + dt * 16 + l15] = oacc[mt][dt][r] / lsum[mt][r];
            }
}

// ---------------------------------------------------------------------------
extern "C" void kernel_launch(void* const* d_in, const int* in_sizes, int n_in,
                              void* d_out, int out_size, void* d_ws, size_t ws_size,
                              hipStream_t stream) {
    const float* x      = (const float*)d_in[0];
    const float* w_qkv  = (const float*)d_in[1];
    const float* b_qkv  = (const float*)d_in[2];
    const float* w_proj = (const float*)d_in[3];
    const float* b_proj = (const float*)d_in[4];
    float* out = (float*)d_out;

    float* xT    = (float*)d_ws;                       // [4][2304][256]
    float* qkvT  = xT + (size_t)kN * kS * kC;          // [4][2304][768]
    float* attnT = qkvT + (size_t)kN * kS * kO;        // [4][2304][256]

    transpose_x<<<dim3(72, 8, 4), 256, 0, stream>>>(x, xT);

    // qkvT[s][o] = xT[s][:] . w_qkv[o][:]  (+b_qkv[o], q cols scaled)
    gemm_bt<0><<<dim3(6, 18, 4), 256, 0, stream>>>(
        xT, w_qkv, b_qkv, qkvT,
        /*K=*/256, /*lda=*/kC, /*ldb=*/kC, /*ldc=*/kO,
        (long long)kS * kC, 0LL, (long long)kS * kO);

    attn_kernel<<<dim3(18, 8, 4), 256, 0, stream>>>(qkvT, attnT);

    // out[o][s] = w_proj[o][:] . attnT[s][:]  (+b_proj[o])
    gemm_bt<1><<<dim3(18, 2, 4), 256, 0, stream>>>(
        w_proj, attnT, b_proj, out,
        /*K=*/256, /*lda=*/kDV, /*ldb=*/kDV, /*ldc=*/kS,
        0LL, (long long)kS * kDV, (long long)kDV * kS);
}

// Round 3
// 194.869 us; speedup vs baseline: 1.2345x; 1.2345x over previous
//
#include <hip/hip_runtime.h>
#include <cstdint>

// Problem constants
constexpr int kN   = 4;
constexpr int kC   = 256;
constexpr int kS   = 2304;   // 48*48
constexpr int kDK  = 256;
constexpr int kDV  = 256;
constexpr int kDH  = 32;     // head dim
constexpr int kO   = 768;    // 2*DK + DV

typedef __bf16    bf16x8 __attribute__((ext_vector_type(8)));
typedef float     f32x4  __attribute__((ext_vector_type(4)));
typedef _Float16  f16;
typedef _Float16  f16x4  __attribute__((ext_vector_type(4)));
typedef _Float16  f16x8  __attribute__((ext_vector_type(8)));

union U4  { uint4 u; bf16x8 v; unsigned short s[8]; };
union F4  { float4 f; float a[4]; };
union UF8 { uint4 u; f16x8 v; f16 h[8]; };
union UF4 { uint2 u; f16x4 v; ushort4 su; };

__device__ inline float bf2f(unsigned short h) {
    unsigned int u = ((unsigned int)h) << 16;
    return __builtin_bit_cast(float, u);
}
__device__ inline unsigned short f2bf(float f) {
    unsigned int u = __builtin_bit_cast(unsigned int, f);
    u += 0x7fff + ((u >> 16) & 1);   // RNE
    return (unsigned short)(u >> 16);
}
__device__ inline void split2(float v, unsigned short& h, unsigned short& l) {
    h = f2bf(v);
    l = f2bf(v - bf2f(h));
}

// ---------------------------------------------------------------------------
// Stage 0: transpose x[n][c][s] -> xT[n][s][c]  (fp32)
// ---------------------------------------------------------------------------
__global__ __launch_bounds__(256) void transpose_x(const float* __restrict__ x,
                                                   float* __restrict__ xT) {
    __shared__ float t[32][33];
    int n  = blockIdx.z;
    int ct = blockIdx.y;     // 8
    int st = blockIdx.x;     // 72
    int lx = threadIdx.x & 31;
    int ly = threadIdx.x >> 5;
    const float* xb = x + (size_t)n * kC * kS;
#pragma unroll
    for (int i = 0; i < 4; i++) {
        int c = ct * 32 + ly + i * 8;
        t[ly + i * 8][lx] = xb[(size_t)c * kS + st * 32 + lx];
    }
    __syncthreads();
    float* xTb = xT + (size_t)n * kS * kC;
#pragma unroll
    for (int i = 0; i < 4; i++) {
        int s = st * 32 + ly + i * 8;
        xTb[(size_t)s * kC + ct * 32 + lx] = t[lx][ly + i * 8];
    }
}

// ---------------------------------------------------------------------------
// Stage 1: QKV GEMM. qkv[s][o] = xT[s][:]·w_qkv[o][:] + b_qkv[o], split-bf16
// (3 MFMAs) for fp32-grade accuracy. Epilogue writes f16 buffers in
// attention-friendly layouts:
//   Kf [nh][s][32], Qf [nh][s][32] (prescaled by DK^-0.5), Vt [nh][32][S].
// Tile 128x128, BK=32, 4 waves, wave 64x64 (4x4 frags). Grid (6,18,4).
// ---------------------------------------------------------------------------
__global__ __launch_bounds__(256) void gemm_qkv(const float* __restrict__ A,   // xT
                                                const float* __restrict__ B,   // w_qkv
                                                const float* __restrict__ bias,
                                                f16* __restrict__ Qf,
                                                f16* __restrict__ Kf,
                                                f16* __restrict__ Vt) {
    int n  = blockIdx.z;
    A += (size_t)n * kS * kC;
    int m0 = blockIdx.y * 128;
    int n0 = blockIdx.x * 128;

    __shared__ unsigned short Ah[128 * 40];
    __shared__ unsigned short Al[128 * 40];
    __shared__ unsigned short Bh[128 * 40];
    __shared__ unsigned short Bl[128 * 40];

    int tid  = threadIdx.x;
    int wid  = tid >> 6;
    int lane = tid & 63;
    int l15  = lane & 15;
    int quad = lane >> 4;
    int wm   = (wid & 1) * 64;
    int wn   = (wid >> 1) * 64;

    f32x4 acc[4][4] = {};

    for (int k0 = 0; k0 < kC; k0 += 32) {
#pragma unroll
        for (int t = 0; t < 4; t++) {
            int chunk = tid + t * 256;
            int row   = chunk >> 3;
            int c4    = (chunk & 7) * 4;
            F4 ga; ga.f = *(const float4*)(A + (size_t)(m0 + row) * kC + k0 + c4);
            ushort4 hv, lv;
            split2(ga.a[0], hv.x, lv.x);
            split2(ga.a[1], hv.y, lv.y);
            split2(ga.a[2], hv.z, lv.z);
            split2(ga.a[3], hv.w, lv.w);
            *(ushort4*)(&Ah[row * 40 + c4]) = hv;
            *(ushort4*)(&Al[row * 40 + c4]) = lv;
            F4 gb; gb.f = *(const float4*)(B + (size_t)(n0 + row) * kC + k0 + c4);
            split2(gb.a[0], hv.x, lv.x);
            split2(gb.a[1], hv.y, lv.y);
            split2(gb.a[2], hv.z, lv.z);
            split2(gb.a[3], hv.w, lv.w);
            *(ushort4*)(&Bh[row * 40 + c4]) = hv;
            *(ushort4*)(&Bl[row * 40 + c4]) = lv;
        }
        __syncthreads();

        bf16x8 ah[4], al[4], bh[4], bl[4];
#pragma unroll
        for (int mt = 0; mt < 4; mt++) {
            U4 u;
            u.u = *(const uint4*)(&Ah[(wm + mt * 16 + l15) * 40 + quad * 8]); ah[mt] = u.v;
            u.u = *(const uint4*)(&Al[(wm + mt * 16 + l15) * 40 + quad * 8]); al[mt] = u.v;
        }
#pragma unroll
        for (int nt = 0; nt < 4; nt++) {
            U4 u;
            u.u = *(const uint4*)(&Bh[(wn + nt * 16 + l15) * 40 + quad * 8]); bh[nt] = u.v;
            u.u = *(const uint4*)(&Bl[(wn + nt * 16 + l15) * 40 + quad * 8]); bl[nt] = u.v;
        }
#pragma unroll
        for (int mt = 0; mt < 4; mt++)
#pragma unroll
            for (int nt = 0; nt < 4; nt++) {
                acc[mt][nt] = __builtin_amdgcn_mfma_f32_16x16x32_bf16(ah[mt], bh[nt], acc[mt][nt], 0, 0, 0);
                acc[mt][nt] = __builtin_amdgcn_mfma_f32_16x16x32_bf16(ah[mt], bl[nt], acc[mt][nt], 0, 0, 0);
                acc[mt][nt] = __builtin_amdgcn_mfma_f32_16x16x32_bf16(al[mt], bh[nt], acc[mt][nt], 0, 0, 0);
            }
        __syncthreads();
    }

    // Epilogue: C-layout D[row=quad*4+r][col=l15]. col -> (section, h, d).
#pragma unroll
    for (int nt = 0; nt < 4; nt++) {
        int col = n0 + wn + nt * 16 + l15;
        float bcol = bias[col];
        int sec = col >> 8;          // 0=K, 1=Q, 2=V  (tile never crosses sections)
        int h   = (col >> 5) & 7;
        int d   = col & 31;
        int nh  = n * 8 + h;
        float scale = (sec == 1) ? 0.0625f : 1.0f;
#pragma unroll
        for (int mt = 0; mt < 4; mt++) {
            int row0 = m0 + wm + mt * 16 + quad * 4;
            if (sec == 2) {
                UF4 w;
#pragma unroll
                for (int r = 0; r < 4; r++) w.v[r] = (f16)(acc[mt][nt][r] + bcol);
                *(ushort4*)(&Vt[((size_t)nh * kDH + d) * kS + row0]) = w.su;
            } else {
                f16* dst = (sec == 0) ? Kf : Qf;
#pragma unroll
                for (int r = 0; r < 4; r++)
                    dst[((size_t)nh * kS + row0 + r) * kDH + d] =
                        (f16)((acc[mt][nt][r] + bcol) * scale);
            }
        }
    }
}

// ---------------------------------------------------------------------------
// Stage 2: attention, LDS-free, barrier-free. One wave per block, 32 q-rows.
// Logits computed transposed: S^T = K·Q^T via 16x16x32 f16 MFMA, so the
// C-layout registers (P[sq=l15][t=quad*4+r]) are directly the B-operand
// fragment of 16x16x16 f16 MFMA for PV (O^T = V^T·P^T). Softmax max-free
// (|logit| < ~2.5). lsum reduced once at the end via shfl_xor(16/32).
// Grid (72, 8, 4) = 2304 one-wave blocks -> 9 waves/CU, perfect balance.
// ---------------------------------------------------------------------------
__global__ __launch_bounds__(64) void attn_f16(const f16* __restrict__ Qf,
                                               const f16* __restrict__ Kf,
                                               const f16* __restrict__ Vt,
                                               f16* __restrict__ attnT) {
    int qw = blockIdx.x;               // 72 tiles of 32 q-rows
    int h  = blockIdx.y, n = blockIdx.z;
    int nh = n * 8 + h;
    int lane = threadIdx.x;
    int l15  = lane & 15;
    int quad = lane >> 4;
    int sqb  = qw * 32;

    const f16* Qb = Qf + (size_t)nh * kS * kDH;
    const f16* Kb = Kf + (size_t)nh * kS * kDH;
    const f16* Vb = Vt + (size_t)nh * kDH * kS;

    f16x8 qf[2];
    {
        UF8 u;
        u.u = *(const uint4*)(Qb + (size_t)(sqb + l15) * kDH + quad * 8);      qf[0] = u.v;
        u.u = *(const uint4*)(Qb + (size_t)(sqb + 16 + l15) * kDH + quad * 8); qf[1] = u.v;
    }

    f32x4 oacc[2][2] = {};     // [dt][sqf]: O^T[d=dt*16+quad*4+r][sq=sqf*16+l15]
    float lsum[2] = {0.f, 0.f};

    // prefetch first K-tile
    f16x8 kfr[4];
#pragma unroll
    for (int tt = 0; tt < 4; tt++) {
        UF8 u; u.u = *(const uint4*)(Kb + (size_t)(tt * 16 + l15) * kDH + quad * 8);
        kfr[tt] = u.v;
    }

    for (int t0 = 0; t0 < kS; t0 += 64) {
        // prefetch next K-tile (last iter reads into adjacent ws buffer: unused)
        f16x8 kn[4];
#pragma unroll
        for (int tt = 0; tt < 4; tt++) {
            UF8 u; u.u = *(const uint4*)(Kb + (size_t)(t0 + 64 + tt * 16 + l15) * kDH + quad * 8);
            kn[tt] = u.v;
        }

        // logits (transposed) + exp, in-register
        f16x4 pf[2][4];      // pf[sqf][tt]: P[sq=l15][t = tt*16 + quad*4 + r]
#pragma unroll
        for (int sqf = 0; sqf < 2; sqf++) {
#pragma unroll
            for (int tt = 0; tt < 4; tt++) {
                f32x4 z = {};
                z = __builtin_amdgcn_mfma_f32_16x16x32_f16(kfr[tt], qf[sqf], z, 0, 0, 0);
                float s = 0.f;
                f16x4 p;
#pragma unroll
                for (int r = 0; r < 4; r++) {
                    float e = __expf(z[r]);
                    s += e;
                    p[r] = (f16)e;
                }
                pf[sqf][tt] = p;
                lsum[sqf] += s;
            }
        }

        // PV: O^T += V^T · P^T, 16x16x16 f16 MFMA, K=16 steps over t
#pragma unroll
        for (int kk = 0; kk < 4; kk++) {
            f16x4 vfr[2];
#pragma unroll
            for (int dt = 0; dt < 2; dt++) {
                UF4 u;
                u.u = *(const uint2*)(Vb + (size_t)(dt * 16 + l15) * kS + t0 + kk * 16 + quad * 4);
                vfr[dt] = u.v;
            }
#pragma unroll
            for (int dt = 0; dt < 2; dt++)
#pragma unroll
                for (int sqf = 0; sqf < 2; sqf++)
                    oacc[dt][sqf] = __builtin_amdgcn_mfma_f32_16x16x16f16(
                        vfr[dt], pf[sqf][kk], oacc[dt][sqf], 0, 0, 0);
        }

#pragma unroll
        for (int tt = 0; tt < 4; tt++) kfr[tt] = kn[tt];
    }

    // final row-sum reduction across quads (lanes with same l15)
#pragma unroll
    for (int sqf = 0; sqf < 2; sqf++) {
        float v = lsum[sqf];
        v += __shfl_xor(v, 16);
        v += __shfl_xor(v, 32);
        lsum[sqf] = v;
    }

    // epilogue: normalize, write attnT[n][s][h*32+d] f16 (8B vector stores)
    f16* ob = attnT + (size_t)n * kS * kDV;
#pragma unroll
    for (int sqf = 0; sqf < 2; sqf++) {
        float inv = 1.0f / lsum[sqf];
        int s = sqb + sqf * 16 + l15;
#pragma unroll
        for (int dt = 0; dt < 2; dt++) {
            UF4 w;
#pragma unroll
            for (int r = 0; r < 4; r++) w.v[r] = (f16)(oacc[dt][sqf][r] * inv);
            *(ushort4*)(ob + (size_t)s * kDV + h * kDH + dt * 16 + quad * 4) = w.su;
        }
    }
}

// ---------------------------------------------------------------------------
// Stage 3: out-proj. out[n][o][s] = w_proj[o][:]·attn[s][:] + b_proj[o].
// Single-f16 MFMA (attn path is already f16-grade). Tile 64(M)x128(N),
// 4 waves, wave 32x64 (2x4 frags). Grid (18, 4, 4) = 288 blocks.
// ---------------------------------------------------------------------------
__global__ __launch_bounds__(256) void gemm_out(const float* __restrict__ Wp,
                                                const f16* __restrict__ attnT,
                                                const float* __restrict__ bias,
                                                float* __restrict__ out) {
    int n  = blockIdx.z;
    int m0 = blockIdx.y * 64;     // o
    int n0 = blockIdx.x * 128;    // s
    const f16* Bb = attnT + (size_t)n * kS * kDV;

    __shared__ f16 As[64 * 40];
    __shared__ f16 Bs[128 * 40];

    int tid  = threadIdx.x;
    int wid  = tid >> 6;
    int lane = tid & 63;
    int l15  = lane & 15;
    int quad = lane >> 4;
    int wm   = (wid & 1) * 32;
    int wn   = (wid >> 1) * 64;

    f32x4 acc[2][4] = {};

    for (int k0 = 0; k0 < kDV; k0 += 32) {
        {   // A: 64x32 fp32 -> f16 (one 16B chunk per thread)
            int row = tid >> 2, c8 = (tid & 3) * 8;
            F4 a0, a1;
            a0.f = *(const float4*)(Wp + (size_t)(m0 + row) * kDV + k0 + c8);
            a1.f = *(const float4*)(Wp + (size_t)(m0 + row) * kDV + k0 + c8 + 4);
            UF8 w;
#pragma unroll
            for (int j = 0; j < 4; j++) w.h[j] = (f16)a0.a[j];
#pragma unroll
            for (int j = 0; j < 4; j++) w.h[j + 4] = (f16)a1.a[j];
            *(uint4*)(&As[row * 40 + c8]) = w.u;
        }
#pragma unroll
        for (int t = 0; t < 2; t++) {   // B: 128x32 f16 copy
            int chunk = tid + t * 256;
            int row = chunk >> 2, c8 = (chunk & 3) * 8;
            *(uint4*)(&Bs[row * 40 + c8]) =
                *(const uint4*)(Bb + (size_t)(n0 + row) * kDV + k0 + c8);
        }
        __syncthreads();

        f16x8 af[2], bf[4];
#pragma unroll
        for (int mt = 0; mt < 2; mt++) {
            UF8 u; u.u = *(const uint4*)(&As[(wm + mt * 16 + l15) * 40 + quad * 8]);
            af[mt] = u.v;
        }
#pragma unroll
        for (int nt = 0; nt < 4; nt++) {
            UF8 u; u.u = *(const uint4*)(&Bs[(wn + nt * 16 + l15) * 40 + quad * 8]);
            bf[nt] = u.v;
        }
#pragma unroll
        for (int mt = 0; mt < 2; mt++)
#pragma unroll
            for (int nt = 0; nt < 4; nt++)
                acc[mt][nt] = __builtin_amdgcn_mfma_f32_16x16x32_f16(af[mt], bf[nt],
                                                                     acc[mt][nt], 0, 0, 0);
        __syncthreads();
    }

#pragma unroll
    for (int nt = 0; nt < 4; nt++) {
        int col = n0 + wn + nt * 16 + l15;   // s
#pragma unroll
        for (int mt = 0; mt < 2; mt++) {
            int row = m0 + wm + mt * 16 + quad * 4;   // o
#pragma unroll
            for (int r = 0; r < 4; r++)
                out[((size_t)n * kDV + row + r) * kS + col] = acc[mt][nt][r] + bias[row + r];
        }
    }
}

// ---------------------------------------------------------------------------
extern "C" void kernel_launch(void* const* d_in, const int* in_sizes, int n_in,
                              void* d_out, int out_size, void* d_ws, size_t ws_size,
                              hipStream_t stream) {
    const float* x      = (const float*)d_in[0];
    const float* w_qkv  = (const float*)d_in[1];
    const float* b_qkv  = (const float*)d_in[2];
    const float* w_proj = (const float*)d_in[3];
    const float* b_proj = (const float*)d_in[4];
    float* out = (float*)d_out;

    constexpr size_t kNS = (size_t)kN * kS;          // 9216
    float* xT    = (float*)d_ws;                     // [4][2304][256] fp32
    f16*   Qf    = (f16*)(xT + kNS * kC);            // [32 nh][2304][32]
    f16*   Kf    = Qf + kNS * kDH * 8 / 8 * 8;       // same size: kNS*kDH*... 
    // (sizes: each of Qf/Kf is 32*2304*32 = kNS*kDK/8*... = 2359296 elems)
    Kf = Qf + (size_t)32 * kS * kDH;
    f16*   Vt    = Kf + (size_t)32 * kS * kDH;       // [32 nh][32][2304]
    f16*   attnT = Vt + (size_t)32 * kS * kDH;       // [4][2304][256]

    transpose_x<<<dim3(72, 8, 4), 256, 0, stream>>>(x, xT);

    gemm_qkv<<<dim3(6, 18, 4), 256, 0, stream>>>(xT, w_qkv, b_qkv, Qf, Kf, Vt);

    attn_f16<<<dim3(72, 8, 4), 64, 0, stream>>>(Qf, Kf, Vt, attnT);

    gemm_out<<<dim3(18, 4, 4), 256, 0, stream>>>(w_proj, attnT, b_proj, out);
}

// Round 5
// 149.456 us; speedup vs baseline: 1.6096x; 1.3039x over previous
//
#include <hip/hip_runtime.h>
#include <cstdint>

// Problem constants
constexpr int kN   = 4;
constexpr int kC   = 256;
constexpr int kS   = 2304;   // 48*48
constexpr int kDK  = 256;
constexpr int kDV  = 256;
constexpr int kDH  = 32;     // head dim
constexpr int kO   = 768;    // 2*DK + DV

typedef __bf16    bf16x8 __attribute__((ext_vector_type(8)));
typedef float     f32x4  __attribute__((ext_vector_type(4)));
typedef _Float16  f16;
typedef _Float16  f16x4  __attribute__((ext_vector_type(4)));
typedef _Float16  f16x8  __attribute__((ext_vector_type(8)));

union U4  { uint4 u; bf16x8 v; unsigned short s[8]; };
union F4  { float4 f; float a[4]; };
union UF8 { uint4 u; f16x8 v; f16 h[8]; };
union UF4 { uint2 u; f16x4 v; ushort4 su; };

#if __has_builtin(__builtin_amdgcn_exp2f)
#define EXP2(x) __builtin_amdgcn_exp2f(x)
#else
#define EXP2(x) exp2f(x)
#endif

__device__ inline float bf2f(unsigned short h) {
    unsigned int u = ((unsigned int)h) << 16;
    return __builtin_bit_cast(float, u);
}
__device__ inline unsigned short f2bf(float f) {
    unsigned int u = __builtin_bit_cast(unsigned int, f);
    u += 0x7fff + ((u >> 16) & 1);   // RNE
    return (unsigned short)(u >> 16);
}
__device__ inline void split2(float v, unsigned short& h, unsigned short& l) {
    h = f2bf(v);
    l = f2bf(v - bf2f(h));
}
// packed f32x2 -> f16x2 (RTZ), returned as raw u32
__device__ inline unsigned int pk2(float a, float b) {
    auto p = __builtin_amdgcn_cvt_pkrtz(a, b);   // __fp16 ext_vector(2)
    return __builtin_bit_cast(unsigned int, p);
}

// ---------------------------------------------------------------------------
// Stage 0: transpose x[n][c][s] -> xT[n][s][c]  (fp32)
// ---------------------------------------------------------------------------
__global__ __launch_bounds__(256) void transpose_x(const float* __restrict__ x,
                                                   float* __restrict__ xT) {
    __shared__ float t[32][33];
    int n  = blockIdx.z;
    int ct = blockIdx.y;     // 8
    int st = blockIdx.x;     // 72
    int lx = threadIdx.x & 31;
    int ly = threadIdx.x >> 5;
    const float* xb = x + (size_t)n * kC * kS;
#pragma unroll
    for (int i = 0; i < 4; i++) {
        int c = ct * 32 + ly + i * 8;
        t[ly + i * 8][lx] = xb[(size_t)c * kS + st * 32 + lx];
    }
    __syncthreads();
    float* xTb = xT + (size_t)n * kS * kC;
#pragma unroll
    for (int i = 0; i < 4; i++) {
        int s = st * 32 + ly + i * 8;
        xTb[(size_t)s * kC + ct * 32 + lx] = t[lx][ly + i * 8];
    }
}

// ---------------------------------------------------------------------------
// Stage 1: QKV GEMM, split-bf16 (3 MFMAs) for fp32-grade accuracy.
// Epilogue writes f16:
//   Kf [nh][s][32], Qf [nh][s][32] (prescaled by DK^-0.5 / ln2 for exp2
//   softmax), Vp [nh][tb=s/16][dt=d/16][lane 64][j 4] -- PV B-operand
//   fragment order, each 16x16 fragment a contiguous 512B block.
// Tile 128x128, BK=32, 4 waves, wave 64x64 (4x4 frags). Grid (6,18,4).
// ---------------------------------------------------------------------------
__global__ __launch_bounds__(256) void gemm_qkv(const float* __restrict__ A,   // xT
                                                const float* __restrict__ B,   // w_qkv
                                                const float* __restrict__ bias,
                                                f16* __restrict__ Qf,
                                                f16* __restrict__ Kf,
                                                f16* __restrict__ Vp) {
    int n  = blockIdx.z;
    A += (size_t)n * kS * kC;
    int m0 = blockIdx.y * 128;
    int n0 = blockIdx.x * 128;

    __shared__ unsigned short Ah[128 * 40];
    __shared__ unsigned short Al[128 * 40];
    __shared__ unsigned short Bh[128 * 40];
    __shared__ unsigned short Bl[128 * 40];

    int tid  = threadIdx.x;
    int wid  = tid >> 6;
    int lane = tid & 63;
    int l15  = lane & 15;
    int quad = lane >> 4;
    int wm   = (wid & 1) * 64;
    int wn   = (wid >> 1) * 64;

    f32x4 acc[4][4] = {};

    for (int k0 = 0; k0 < kC; k0 += 32) {
#pragma unroll
        for (int t = 0; t < 4; t++) {
            int chunk = tid + t * 256;
            int row   = chunk >> 3;
            int c4    = (chunk & 7) * 4;
            F4 ga; ga.f = *(const float4*)(A + (size_t)(m0 + row) * kC + k0 + c4);
            ushort4 hv, lv;
            split2(ga.a[0], hv.x, lv.x);
            split2(ga.a[1], hv.y, lv.y);
            split2(ga.a[2], hv.z, lv.z);
            split2(ga.a[3], hv.w, lv.w);
            *(ushort4*)(&Ah[row * 40 + c4]) = hv;
            *(ushort4*)(&Al[row * 40 + c4]) = lv;
            F4 gb; gb.f = *(const float4*)(B + (size_t)(n0 + row) * kC + k0 + c4);
            split2(gb.a[0], hv.x, lv.x);
            split2(gb.a[1], hv.y, lv.y);
            split2(gb.a[2], hv.z, lv.z);
            split2(gb.a[3], hv.w, lv.w);
            *(ushort4*)(&Bh[row * 40 + c4]) = hv;
            *(ushort4*)(&Bl[row * 40 + c4]) = lv;
        }
        __syncthreads();

        bf16x8 ah[4], al[4], bh[4], bl[4];
#pragma unroll
        for (int mt = 0; mt < 4; mt++) {
            U4 u;
            u.u = *(const uint4*)(&Ah[(wm + mt * 16 + l15) * 40 + quad * 8]); ah[mt] = u.v;
            u.u = *(const uint4*)(&Al[(wm + mt * 16 + l15) * 40 + quad * 8]); al[mt] = u.v;
        }
#pragma unroll
        for (int nt = 0; nt < 4; nt++) {
            U4 u;
            u.u = *(const uint4*)(&Bh[(wn + nt * 16 + l15) * 40 + quad * 8]); bh[nt] = u.v;
            u.u = *(const uint4*)(&Bl[(wn + nt * 16 + l15) * 40 + quad * 8]); bl[nt] = u.v;
        }
#pragma unroll
        for (int mt = 0; mt < 4; mt++)
#pragma unroll
            for (int nt = 0; nt < 4; nt++) {
                acc[mt][nt] = __builtin_amdgcn_mfma_f32_16x16x32_bf16(ah[mt], bh[nt], acc[mt][nt], 0, 0, 0);
                acc[mt][nt] = __builtin_amdgcn_mfma_f32_16x16x32_bf16(ah[mt], bl[nt], acc[mt][nt], 0, 0, 0);
                acc[mt][nt] = __builtin_amdgcn_mfma_f32_16x16x32_bf16(al[mt], bh[nt], acc[mt][nt], 0, 0, 0);
            }
        __syncthreads();
    }

    // Epilogue: C-layout D[row=quad*4+r][col=l15]. col -> (section, h, d).
    // Q prescale folds DK^-0.5 and 1/ln2 (softmax done in exp2).
    constexpr float kQScale = 0.0625f * 1.4426950408889634f;
#pragma unroll
    for (int nt = 0; nt < 4; nt++) {
        int col = n0 + wn + nt * 16 + l15;
        float bcol = bias[col];
        int sec = col >> 8;          // 0=K, 1=Q, 2=V  (tile never crosses sections)
        int h   = (col >> 5) & 7;
        int d   = col & 31;
        int nh  = n * 8 + h;
#pragma unroll
        for (int mt = 0; mt < 4; mt++) {
            int row0 = m0 + wm + mt * 16 + quad * 4;
            if (sec == 2) {
                UF4 w;
#pragma unroll
                for (int r = 0; r < 4; r++) w.v[r] = (f16)(acc[mt][nt][r] + bcol);
                int dt = (col >> 4) & 1;
                size_t off = ((((size_t)nh * 144 + (row0 >> 4)) * 2 + dt) * 64
                              + quad * 16 + l15) * 4;
                *(ushort4*)(Vp + off) = w.su;   // coalesced: 8B per lane, lane-ordered
            } else if (sec == 0) {
#pragma unroll
                for (int r = 0; r < 4; r++)
                    Kf[((size_t)nh * kS + row0 + r) * kDH + d] = (f16)(acc[mt][nt][r] + bcol);
            } else {
#pragma unroll
                for (int r = 0; r < 4; r++)
                    Qf[((size_t)nh * kS + row0 + r) * kDH + d] =
                        (f16)((acc[mt][nt][r] + bcol) * kQScale);
            }
        }
    }
}

// ---------------------------------------------------------------------------
// Stage 2: attention, LDS-free, barrier-free, fully prefetched.
// One wave per block, 32 q-rows. Logits transposed (S^T = K·Q^T, 16x16x32),
// C-layout == PV B-operand layout, so exp2 happens in-register and P feeds
// the 16x16x16 PV MFMA directly. V fragments are contiguous 512B blocks
// (coalesced uint2/lane). K and V both prefetched one t-tile (64) ahead.
// Grid (72, 8, 4) = 2304 one-wave blocks = 9 waves/CU.
// ---------------------------------------------------------------------------
__global__ __launch_bounds__(64) void attn_f16(const f16* __restrict__ Qf,
                                               const f16* __restrict__ Kf,
                                               const f16* __restrict__ Vp,
                                               f16* __restrict__ attnT) {
    int qw = blockIdx.x;               // 72 tiles of 32 q-rows
    int h  = blockIdx.y, n = blockIdx.z;
    int nh = n * 8 + h;
    int lane = threadIdx.x;
    int l15  = lane & 15;
    int quad = lane >> 4;
    int sqb  = qw * 32;

    const f16* Qb = Qf + (size_t)nh * kS * kDH;
    const f16* kp = Kf + (size_t)nh * kS * kDH + l15 * kDH + quad * 8;
    const f16* vp = Vp + (size_t)nh * 144 * 512 + lane * 4;

    f16x8 qf[2];
    {
        UF8 u;
        u.u = *(const uint4*)(Qb + (size_t)(sqb + l15) * kDH + quad * 8);      qf[0] = u.v;
        u.u = *(const uint4*)(Qb + (size_t)(sqb + 16 + l15) * kDH + quad * 8); qf[1] = u.v;
    }

    f32x4 oacc[2][2] = {};     // [dt][sqf]: O^T[d=dt*16+quad*4+r][sq=sqf*16+l15]
    float lsum[2] = {0.f, 0.f};

    // prefetch t-tile 0
    f16x8 kfr[4];
    f16x4 vfr[4][2];
#pragma unroll
    for (int tt = 0; tt < 4; tt++) {
        UF8 u; u.u = *(const uint4*)(kp + tt * 512); kfr[tt] = u.v;
    }
#pragma unroll
    for (int kk = 0; kk < 4; kk++)
#pragma unroll
        for (int dt = 0; dt < 2; dt++) {
            UF4 u; u.u = *(const uint2*)(vp + kk * 512 + dt * 256); vfr[kk][dt] = u.v;
        }

    for (int t0 = 0; t0 < kS; t0 += 64) {
        // prefetch next t-tile (final iter over-reads into adjacent ws buffers)
        f16x8 kn[4];
        f16x4 vn[4][2];
#pragma unroll
        for (int tt = 0; tt < 4; tt++) {
            UF8 u; u.u = *(const uint4*)(kp + 2048 + tt * 512); kn[tt] = u.v;
        }
#pragma unroll
        for (int kk = 0; kk < 4; kk++)
#pragma unroll
            for (int dt = 0; dt < 2; dt++) {
                UF4 u; u.u = *(const uint2*)(vp + 2048 + kk * 512 + dt * 256); vn[kk][dt] = u.v;
            }

        // logits (transposed) + exp2 + pack, in-register
        f16x4 pf[2][4];      // pf[sqf][tt]: P^T[t=tt*16+quad*4+r][sq=l15]
#pragma unroll
        for (int sqf = 0; sqf < 2; sqf++)
#pragma unroll
            for (int tt = 0; tt < 4; tt++) {
                f32x4 z = {};
                z = __builtin_amdgcn_mfma_f32_16x16x32_f16(kfr[tt], qf[sqf], z, 0, 0, 0);
                float e0 = EXP2(z[0]), e1 = EXP2(z[1]);
                float e2 = EXP2(z[2]), e3 = EXP2(z[3]);
                lsum[sqf] += (e0 + e1) + (e2 + e3);
                UF4 w;
                w.u.x = pk2(e0, e1);
                w.u.y = pk2(e2, e3);
                pf[sqf][tt] = w.v;
            }

        // PV: O^T += V^T · P^T
#pragma unroll
        for (int kk = 0; kk < 4; kk++)
#pragma unroll
            for (int dt = 0; dt < 2; dt++)
#pragma unroll
                for (int sqf = 0; sqf < 2; sqf++)
                    oacc[dt][sqf] = __builtin_amdgcn_mfma_f32_16x16x16f16(
                        vfr[kk][dt], pf[sqf][kk], oacc[dt][sqf], 0, 0, 0);

#pragma unroll
        for (int tt = 0; tt < 4; tt++) kfr[tt] = kn[tt];
#pragma unroll
        for (int kk = 0; kk < 4; kk++) {
            vfr[kk][0] = vn[kk][0];
            vfr[kk][1] = vn[kk][1];
        }
        kp += 2048;
        vp += 2048;
    }

    // final row-sum reduction across quads (lanes with same l15)
#pragma unroll
    for (int sqf = 0; sqf < 2; sqf++) {
        float v = lsum[sqf];
        v += __shfl_xor(v, 16);
        v += __shfl_xor(v, 32);
        lsum[sqf] = v;
    }

    // epilogue: normalize, write attnT[n][s][h*32+d] f16 (8B vector stores)
    f16* ob = attnT + (size_t)n * kS * kDV;
#pragma unroll
    for (int sqf = 0; sqf < 2; sqf++) {
        float inv = 1.0f / lsum[sqf];
        int s = sqb + sqf * 16 + l15;
#pragma unroll
        for (int dt = 0; dt < 2; dt++) {
            UF4 w;
#pragma unroll
            for (int r = 0; r < 4; r++) w.v[r] = (f16)(oacc[dt][sqf][r] * inv);
            *(ushort4*)(ob + (size_t)s * kDV + h * kDH + dt * 16 + quad * 4) = w.su;
        }
    }
}

// ---------------------------------------------------------------------------
// Stage 3: out-proj. out[n][o][s] = w_proj[o][:]·attn[s][:] + b_proj[o].
// Single-f16 MFMA. Tile 64(M)x128(N), 4 waves, wave 32x64. Grid (18,4,4).
// ---------------------------------------------------------------------------
__global__ __launch_bounds__(256) void gemm_out(const float* __restrict__ Wp,
                                                const f16* __restrict__ attnT,
                                                const float* __restrict__ bias,
                                                float* __restrict__ out) {
    int n  = blockIdx.z;
    int m0 = blockIdx.y * 64;     // o
    int n0 = blockIdx.x * 128;    // s
    const f16* Bb = attnT + (size_t)n * kS * kDV;

    __shared__ f16 As[64 * 40];
    __shared__ f16 Bs[128 * 40];

    int tid  = threadIdx.x;
    int wid  = tid >> 6;
    int lane = tid & 63;
    int l15  = lane & 15;
    int quad = lane >> 4;
    int wm   = (wid & 1) * 32;
    int wn   = (wid >> 1) * 64;

    f32x4 acc[2][4] = {};

    for (int k0 = 0; k0 < kDV; k0 += 32) {
        {   // A: 64x32 fp32 -> f16 (one 16B chunk per thread)
            int row = tid >> 2, c8 = (tid & 3) * 8;
            F4 a0, a1;
            a0.f = *(const float4*)(Wp + (size_t)(m0 + row) * kDV + k0 + c8);
            a1.f = *(const float4*)(Wp + (size_t)(m0 + row) * kDV + k0 + c8 + 4);
            UF8 w;
#pragma unroll
            for (int j = 0; j < 4; j++) w.h[j] = (f16)a0.a[j];
#pragma unroll
            for (int j = 0; j < 4; j++) w.h[j + 4] = (f16)a1.a[j];
            *(uint4*)(&As[row * 40 + c8]) = w.u;
        }
#pragma unroll
        for (int t = 0; t < 2; t++) {   // B: 128x32 f16 copy
            int chunk = tid + t * 256;
            int row = chunk >> 2, c8 = (chunk & 3) * 8;
            *(uint4*)(&Bs[row * 40 + c8]) =
                *(const uint4*)(Bb + (size_t)(n0 + row) * kDV + k0 + c8);
        }
        __syncthreads();

        f16x8 af[2], bf[4];
#pragma unroll
        for (int mt = 0; mt < 2; mt++) {
            UF8 u; u.u = *(const uint4*)(&As[(wm + mt * 16 + l15) * 40 + quad * 8]);
            af[mt] = u.v;
        }
#pragma unroll
        for (int nt = 0; nt < 4; nt++) {
            UF8 u; u.u = *(const uint4*)(&Bs[(wn + nt * 16 + l15) * 40 + quad * 8]);
            bf[nt] = u.v;
        }
#pragma unroll
        for (int mt = 0; mt < 2; mt++)
#pragma unroll
            for (int nt = 0; nt < 4; nt++)
                acc[mt][nt] = __builtin_amdgcn_mfma_f32_16x16x32_f16(af[mt], bf[nt],
                                                                     acc[mt][nt], 0, 0, 0);
        __syncthreads();
    }

#pragma unroll
    for (int nt = 0; nt < 4; nt++) {
        int col = n0 + wn + nt * 16 + l15;   // s
#pragma unroll
        for (int mt = 0; mt < 2; mt++) {
            int row = m0 + wm + mt * 16 + quad * 4;   // o
#pragma unroll
            for (int r = 0; r < 4; r++)
                out[((size_t)n * kDV + row + r) * kS + col] = acc[mt][nt][r] + bias[row + r];
        }
    }
}

// ---------------------------------------------------------------------------
extern "C" void kernel_launch(void* const* d_in, const int* in_sizes, int n_in,
                              void* d_out, int out_size, void* d_ws, size_t ws_size,
                              hipStream_t stream) {
    const float* x      = (const float*)d_in[0];
    const float* w_qkv  = (const float*)d_in[1];
    const float* b_qkv  = (const float*)d_in[2];
    const float* w_proj = (const float*)d_in[3];
    const float* b_proj = (const float*)d_in[4];
    float* out = (float*)d_out;

    constexpr size_t kHeadElems = (size_t)32 * kS * kDH;   // per-tensor f16 elems (2.36M)
    float* xT    = (float*)d_ws;                           // [4][2304][256] fp32
    f16*   Qf    = (f16*)(xT + (size_t)kN * kS * kC);      // [32 nh][2304][32]
    f16*   Kf    = Qf + kHeadElems;                        // [32 nh][2304][32]
    f16*   Vp    = Kf + kHeadElems;                        // [32 nh][144][2][64][4]
    f16*   attnT = Vp + kHeadElems;                        // [4][2304][256]

    transpose_x<<<dim3(72, 8, 4), 256, 0, stream>>>(x, xT);

    gemm_qkv<<<dim3(6, 18, 4), 256, 0, stream>>>(xT, w_qkv, b_qkv, Qf, Kf, Vp);

    attn_f16<<<dim3(72, 8, 4), 64, 0, stream>>>(Qf, Kf, Vp, attnT);

    gemm_out<<<dim3(18, 4, 4), 256, 0, stream>>>(w_proj, attnT, b_proj, out);
}